// Round 1
// baseline (187.509 us; speedup 1.0000x reference)
//
#include <hip/hip_runtime.h>
#include <stdint.h>

typedef unsigned short u16;
typedef unsigned int   u32;
typedef short short8 __attribute__((ext_vector_type(8)));
typedef float f32x4  __attribute__((ext_vector_type(4)));

// ---------- helpers ----------
__device__ __forceinline__ u16 f2bf(float f){
  u32 u = __builtin_bit_cast(u32, f);
  u32 r = (u + 0x7FFFu + ((u >> 16) & 1u)) >> 16;   // RNE
  return (u16)r;
}
__device__ __forceinline__ u32 packbf(float a, float b){
  return (u32)f2bf(a) | ((u32)f2bf(b) << 16);
}

// ---------- x f32 -> bf16 ----------
__global__ __launch_bounds__(256) void k_cvt_bf16(const float* __restrict__ x,
                                                  u16* __restrict__ y, int n8){
  int i = blockIdx.x * 256 + threadIdx.x;
  if (i >= n8) return;
  const float4* p = (const float4*)x + (size_t)i * 2;
  float4 a = p[0], b = p[1];
  short8 o;
  o[0] = f2bf(a.x); o[1] = f2bf(a.y); o[2] = f2bf(a.z); o[3] = f2bf(a.w);
  o[4] = f2bf(b.x); o[5] = f2bf(b.y); o[6] = f2bf(b.z); o[7] = f2bf(b.w);
  *(short8*)(y + (size_t)i * 8) = o;
}

// ---------- weight transpose: in f32[R][C] -> out bf16[C][R] ----------
__global__ __launch_bounds__(256) void k_transpose_w(const float* __restrict__ in,
                                                     u16* __restrict__ out, int R, int C){
  __shared__ float tile[32][33];
  int nc = C >> 5;
  int cb = blockIdx.x % nc, rb = blockIdx.x / nc;
  int tx = threadIdx.x & 31, ty = threadIdx.x >> 5;
#pragma unroll
  for (int i = 0; i < 4; ++i){
    int r = rb * 32 + ty + i * 8;
    tile[ty + i * 8][tx] = in[(size_t)r * C + cb * 32 + tx];
  }
  __syncthreads();
#pragma unroll
  for (int i = 0; i < 4; ++i){
    int c = cb * 32 + ty + i * 8;
    out[(size_t)c * R + rb * 32 + tx] = f2bf(tile[tx][ty + i * 8]);
  }
}

// ---------- GEMM: C[M][N] = A[M][K](bf16) * Bt[N][K](bf16)^T, fp32 accum ----------
// 128x128 tile, BK=32, 256 threads = 4 waves (2x2), each wave 64x64 via 4x4 16x16x32 MFMA.
template<typename CT>
__global__ __launch_bounds__(256, 2) void k_gemm_bt(const u16* __restrict__ A,
                                                    const u16* __restrict__ Bt,
                                                    CT* __restrict__ C,
                                                    int M, int N, int K){
  __shared__ u16 As[128 * 40];   // pad 32->40 ushort: frag-read stride 80B -> 2-way max
  __shared__ u16 Bs[128 * 40];
  int tid  = threadIdx.x;
  int lane = tid & 63, wid = tid >> 6;
  int l16 = lane & 15, g4 = lane >> 4;
  int wm = wid >> 1, wn = wid & 1;
  int nb = N >> 7;
  int bm = blockIdx.x / nb, bn = blockIdx.x % nb;

  int rr0 = tid >> 2;          // rows 0..63
  int rr1 = rr0 + 64;          // rows 64..127
  int cc  = (tid & 3) * 8;     // ushort col within BK

  const u16* Ab = A  + (size_t)(bm * 128) * K;
  const u16* Bb = Bt + (size_t)(bn * 128) * K;

  f32x4 zero4 = {0.f, 0.f, 0.f, 0.f};
  f32x4 acc[4][4];
#pragma unroll
  for (int i = 0; i < 4; ++i)
#pragma unroll
    for (int j = 0; j < 4; ++j) acc[i][j] = zero4;

  int nk = K >> 5;
  short8 ga0 = *(const short8*)(Ab + (size_t)rr0 * K + cc);
  short8 ga1 = *(const short8*)(Ab + (size_t)rr1 * K + cc);
  short8 gb0 = *(const short8*)(Bb + (size_t)rr0 * K + cc);
  short8 gb1 = *(const short8*)(Bb + (size_t)rr1 * K + cc);

  for (int kt = 0; kt < nk; ++kt){
    __syncthreads();
    *(short8*)&As[rr0 * 40 + cc] = ga0;
    *(short8*)&As[rr1 * 40 + cc] = ga1;
    *(short8*)&Bs[rr0 * 40 + cc] = gb0;
    *(short8*)&Bs[rr1 * 40 + cc] = gb1;
    __syncthreads();
    if (kt + 1 < nk){           // issue next-tile loads under this tile's MFMA
      int ko = (kt + 1) * 32;
      ga0 = *(const short8*)(Ab + (size_t)rr0 * K + ko + cc);
      ga1 = *(const short8*)(Ab + (size_t)rr1 * K + ko + cc);
      gb0 = *(const short8*)(Bb + (size_t)rr0 * K + ko + cc);
      gb1 = *(const short8*)(Bb + (size_t)rr1 * K + ko + cc);
    }
    short8 af[4], bfr[4];
#pragma unroll
    for (int mt = 0; mt < 4; ++mt)
      af[mt] = *(const short8*)&As[(wm * 64 + mt * 16 + l16) * 40 + g4 * 8];
#pragma unroll
    for (int nt = 0; nt < 4; ++nt)
      bfr[nt] = *(const short8*)&Bs[(wn * 64 + nt * 16 + l16) * 40 + g4 * 8];
#pragma unroll
    for (int mt = 0; mt < 4; ++mt)
#pragma unroll
      for (int nt = 0; nt < 4; ++nt)
        acc[mt][nt] = __builtin_amdgcn_mfma_f32_16x16x32_bf16(af[mt], bfr[nt], acc[mt][nt], 0, 0, 0);
  }

#pragma unroll
  for (int mt = 0; mt < 4; ++mt)
#pragma unroll
    for (int nt = 0; nt < 4; ++nt)
#pragma unroll
      for (int r = 0; r < 4; ++r){
        int row = bm * 128 + wm * 64 + mt * 16 + g4 * 4 + r;
        int col = bn * 128 + wn * 64 + nt * 16 + l16;
        float vv = acc[mt][nt][r];
        if constexpr (sizeof(CT) == 2) C[(size_t)row * N + col] = (CT)f2bf(vv);
        else                           C[(size_t)row * N + col] = (CT)vv;
      }
}

// ---------- V transpose: c1 V-part [bv*256+s][2560+n*64+h] -> vt[(bv*8+n)*64+h][256 s] ----------
__global__ __launch_bounds__(256) void k_vt(const u16* __restrict__ c1, u16* __restrict__ vt){
  __shared__ u16 tile[64][72];
  int bid = blockIdx.x;
  int st = bid & 3, n = (bid >> 2) & 7, bv = bid >> 5;   // bv = b*8+v (0..15)
  int t = threadIdx.x;
  int sr = t >> 2, sc = t & 3;
  const u16* src = c1 + (size_t)(bv * 256 + st * 64 + sr) * 3072 + 2560 + n * 64 + sc * 16;
  short8 a = *(const short8*)src;
  short8 b = *(const short8*)(src + 8);
  *(short8*)&tile[sr][sc * 16]     = a;
  *(short8*)&tile[sr][sc * 16 + 8] = b;
  __syncthreads();
  int h = t >> 2, c2 = t & 3;
  short8 o0, o1;
#pragma unroll
  for (int j = 0; j < 8; ++j) o0[j] = (short)tile[c2 * 16 + j][h];
#pragma unroll
  for (int j = 0; j < 8; ++j) o1[j] = (short)tile[c2 * 16 + 8 + j][h];
  u16* dst = vt + (size_t)((bv * 8 + n) * 64 + h) * 256 + st * 64 + c2 * 16;
  *(short8*)dst       = o0;
  *(short8*)(dst + 8) = o1;
}

// ---------- fused GQA neighbor attention ----------
// block = (b, v, n, qtile64); 4 waves = 4 GQA groups sharing K/V LDS.
// swapped QK^T: mfma(K,Q) -> S^T, softmax row = lane&15; P via per-wave LDS to PV A-frag.
__global__ __launch_bounds__(256, 2) void k_attn(const u16* __restrict__ c1,
                                                 const u16* __restrict__ vt,
                                                 u16* __restrict__ att){
  __shared__ u16 Klds[64][72];       // [key][hd], pad 72
  __shared__ u16 Vlds[64][72];       // [hd][key], pad 72
  __shared__ u16 Plds[4][16][72];    // per-wave [qrow][key]
  int bid = blockIdx.x;
  int qt = bid & 3, n = (bid >> 2) & 7, v = (bid >> 5) & 7, b = bid >> 8;
  int tid = threadIdx.x;
  int g = tid >> 6, lane = tid & 63, l16 = lane & 15, g4 = lane >> 4;
  int bv = b * 8 + v;
  int rowQ = bv * 256 + qt * 64;
  int qcol = n * 256 + g * 64;
  const float SC2 = 0.18033688011112042f;   // log2(e)/8

  // hoist Q fragments (B-operand: col=qrow=l16, k=hd)
  short8 qf[4][2];
#pragma unroll
  for (int qi = 0; qi < 4; ++qi)
#pragma unroll
    for (int kk = 0; kk < 2; ++kk)
      qf[qi][kk] = *(const short8*)(c1 + (size_t)(rowQ + qi * 16 + l16) * 3072
                                     + qcol + kk * 32 + g4 * 8);

  f32x4 zero4 = {0.f, 0.f, 0.f, 0.f};
  f32x4 O[4][4];
#pragma unroll
  for (int i = 0; i < 4; ++i)
#pragma unroll
    for (int j = 0; j < 4; ++j) O[i][j] = zero4;
  float m2[4]   = {-3.0e38f, -3.0e38f, -3.0e38f, -3.0e38f};
  float lsum[4] = {0.f, 0.f, 0.f, 0.f};

  int sr = tid >> 2, sc = tid & 3;
  short8 k0, k1, v0, v1;
  {
    int vn = (v + 7) & 7;
    const u16* ks = c1 + (size_t)((b * 8 + vn) * 256 + sr) * 3072 + 2048 + n * 64 + sc * 16;
    k0 = *(const short8*)ks; k1 = *(const short8*)(ks + 8);
    const u16* vs = vt + (size_t)(((b * 8 + vn) * 8 + n) * 64 + sr) * 256 + sc * 16;
    v0 = *(const short8*)vs; v1 = *(const short8*)(vs + 8);
  }

  for (int ti = 0; ti < 8; ++ti){
    __syncthreads();
    *(short8*)&Klds[sr][sc * 16]     = k0;
    *(short8*)&Klds[sr][sc * 16 + 8] = k1;
    *(short8*)&Vlds[sr][sc * 16]     = v0;
    *(short8*)&Vlds[sr][sc * 16 + 8] = v1;
    __syncthreads();
    if (ti < 7){
      int tn = ti + 1;
      int vn = (tn < 4) ? ((v + 7) & 7) : ((v + 1) & 7);
      int tb = (tn & 3) * 64;
      const u16* ks = c1 + (size_t)((b * 8 + vn) * 256 + tb + sr) * 3072 + 2048 + n * 64 + sc * 16;
      k0 = *(const short8*)ks; k1 = *(const short8*)(ks + 8);
      const u16* vs = vt + (size_t)(((b * 8 + vn) * 8 + n) * 64 + sr) * 256 + tb + sc * 16;
      v0 = *(const short8*)vs; v1 = *(const short8*)(vs + 8);
    }
    short8 kf[4][2], vf[2][4];
#pragma unroll
    for (int kt = 0; kt < 4; ++kt)
#pragma unroll
      for (int ks = 0; ks < 2; ++ks)
        kf[kt][ks] = *(const short8*)&Klds[kt * 16 + l16][ks * 32 + g4 * 8];
#pragma unroll
    for (int ks = 0; ks < 2; ++ks)
#pragma unroll
      for (int hi = 0; hi < 4; ++hi)
        vf[ks][hi] = *(const short8*)&Vlds[hi * 16 + l16][ks * 32 + g4 * 8];

#pragma unroll
    for (int qi = 0; qi < 4; ++qi){
      f32x4 sa[4];
#pragma unroll
      for (int kt = 0; kt < 4; ++kt){
        sa[kt] = zero4;
#pragma unroll
        for (int ks = 0; ks < 2; ++ks)
          sa[kt] = __builtin_amdgcn_mfma_f32_16x16x32_bf16(kf[kt][ks], qf[qi][ks], sa[kt], 0, 0, 0);
      }
      // softmax (exp2 domain), qrow = l16; keys spread over g4 and kt
      float smax = -3.0e38f;
#pragma unroll
      for (int kt = 0; kt < 4; ++kt)
#pragma unroll
        for (int r = 0; r < 4; ++r){
          float s = sa[kt][r] * SC2;
          sa[kt][r] = s;
          smax = fmaxf(smax, s);
        }
      smax = fmaxf(smax, __shfl_xor(smax, 16));
      smax = fmaxf(smax, __shfl_xor(smax, 32));
      float mnew  = fmaxf(m2[qi], smax);
      float alpha = exp2f(m2[qi] - mnew);
      m2[qi] = mnew;
      float psum = 0.f;
      u32 w[4][2];
#pragma unroll
      for (int kt = 0; kt < 4; ++kt){
        float p0 = exp2f(sa[kt][0] - mnew);
        float p1 = exp2f(sa[kt][1] - mnew);
        float p2 = exp2f(sa[kt][2] - mnew);
        float p3 = exp2f(sa[kt][3] - mnew);
        psum += (p0 + p1) + (p2 + p3);
        w[kt][0] = packbf(p0, p1);
        w[kt][1] = packbf(p2, p3);
      }
      psum += __shfl_xor(psum, 16);
      psum += __shfl_xor(psum, 32);
      lsum[qi] = lsum[qi] * alpha + psum;
      // P -> per-wave LDS (key = kt*16 + g4*4 + {0..3}, qrow = l16)
      u32* prow = (u32*)&Plds[g][l16][0];
#pragma unroll
      for (int kt = 0; kt < 4; ++kt){
        prow[kt * 8 + g4 * 2]     = w[kt][0];
        prow[kt * 8 + g4 * 2 + 1] = w[kt][1];
      }
      // rescale O (O rows = g4*4+r -> broadcast alpha from lane g4*4+r)
      float ab[4];
#pragma unroll
      for (int r = 0; r < 4; ++r) ab[r] = __shfl(alpha, g4 * 4 + r);
#pragma unroll
      for (int hi = 0; hi < 4; ++hi)
#pragma unroll
        for (int r = 0; r < 4; ++r) O[qi][hi][r] *= ab[r];
      // PV
      short8 pa[2];
#pragma unroll
      for (int ks = 0; ks < 2; ++ks)
        pa[ks] = *(const short8*)&Plds[g][l16][ks * 32 + g4 * 8];
#pragma unroll
      for (int hi = 0; hi < 4; ++hi)
#pragma unroll
        for (int ks = 0; ks < 2; ++ks)
          O[qi][hi] = __builtin_amdgcn_mfma_f32_16x16x32_bf16(pa[ks], vf[ks][hi], O[qi][hi], 0, 0, 0);
    }
  }
  // epilogue: divide by l, write bf16
#pragma unroll
  for (int qi = 0; qi < 4; ++qi){
    float lb[4];
#pragma unroll
    for (int r = 0; r < 4; ++r) lb[r] = 1.0f / __shfl(lsum[qi], g4 * 4 + r);
#pragma unroll
    for (int hi = 0; hi < 4; ++hi)
#pragma unroll
      for (int r = 0; r < 4; ++r){
        int row = rowQ + qi * 16 + g4 * 4 + r;
        int col = qcol + hi * 16 + l16;
        att[(size_t)row * 2048 + col] = f2bf(O[qi][hi][r] * lb[r]);
      }
  }
}

extern "C" void kernel_launch(void* const* d_in, const int* in_sizes, int n_in,
                              void* d_out, int out_size, void* d_ws, size_t ws_size,
                              hipStream_t stream){
  const float* x   = (const float*)d_in[0];
  const float* wq  = (const float*)d_in[1];
  const float* wkv = (const float*)d_in[2];
  const float* wo  = (const float*)d_in[3];
  float* out = (float*)d_out;
  char* ws = (char*)d_ws;

  // workspace layout (67,108,864 B total)
  u16* x_bf  = (u16*)(ws);               // [4096][2048] bf16, 16.78 MB (aliased by att)
  u16* wqkvt = (u16*)(ws + 16777216);    // [3072][2048] bf16, 12.58 MB
  u16* wot   = (u16*)(ws + 29360128);    // [2048][2048] bf16,  8.39 MB
  u16* c1    = (u16*)(ws + 37748736);    // [4096][3072] bf16, 25.17 MB (Q|K|V)
  u16* vt    = (u16*)(ws + 62914560);    // [16*8][64][256] bf16, 4.19 MB
  u16* att   = x_bf;                     // alias: x_bf dead after GEMM1

  k_cvt_bf16<<<4096, 256, 0, stream>>>(x, x_bf, 1048576);
  k_transpose_w<<<4096, 256, 0, stream>>>(wq,  wqkvt,               2048, 2048);
  k_transpose_w<<<2048, 256, 0, stream>>>(wkv, wqkvt + 2048 * 2048, 2048, 1024);
  k_transpose_w<<<4096, 256, 0, stream>>>(wo,  wot,                 2048, 2048);
  // QKV projection: [4096,2048] x [2048,3072] -> c1 bf16
  k_gemm_bt<u16><<<768, 256, 0, stream>>>(x_bf, wqkvt, c1, 4096, 3072, 2048);
  k_vt<<<512, 256, 0, stream>>>(c1, vt);
  k_attn<<<512, 256, 0, stream>>>(c1, vt, att);
  // output projection: [4096,2048] x [2048,2048] -> f32 out
  k_gemm_bt<float><<<512, 256, 0, stream>>>(att, wot, out, 4096, 2048, 2048);
}